// Round 11
// baseline (31.065 us; speedup 1.0000x reference)
//
#include <hip/hip_runtime.h>

#define MARGIN 0.1f
#define NBEST 64
#define RPW 4          // rows per wave (1024 blocks -> 4 waves/SIMD occupancy)

// ws byte layout (cascade path; zeroed by hipMemsetAsync each call):
//   [0      .. 4095]  slot[g]  : float accumulator, g*64 (64 groups, 64B apart)
//   [4096   .. 8191]  c1[g]    : u32 arrival counter, 4096 + g*64
//   [8192   .. 8255]  s2 (float), c2 (u32)
//   [65536  .. ]      fallback per-block partials (two-kernel path only)

__global__ __launch_bounds__(256)
void sml_kernel(const float* __restrict__ scores,
                const unsigned int* __restrict__ wr32,
                float* __restrict__ ws, float* __restrict__ out,
                int B, int gper /*blocks per group; 0 => fallback path*/)
{
    const int lane = threadIdx.x & 63;
    const int wib  = threadIdx.x >> 6;                 // wave-in-block 0..3
    const int b0   = (blockIdx.x * 4 + wib) * RPW;     // first row of wave

    // werRank width probe (int64 vs int32), wave-uniform: int64 values in
    // [0,64) -> every odd int32 word is 0.
    unsigned int probe = wr32[2 * lane + 1];
    const bool is64 = (__all(probe == 0u) != 0);

    // Gather: lane owns column i=lane of each of its 4 rows.
    unsigned int rk[RPW];
    #pragma unroll
    for (int r = 0; r < RPW; ++r) {
        int bc = min(b0 + r, B - 1);
        rk[r] = is64 ? wr32[2 * (bc * NBEST + lane)] : wr32[bc * NBEST + lane];
    }
    float gv[RPW];
    #pragma unroll
    for (int r = 0; r < RPW; ++r) {
        int bc = min(b0 + r, B - 1);
        gv[r] = scores[bc * NBEST + (int)(rk[r] & (NBEST - 1))];
    }

    __shared__ float4 q4[4][NBEST];      // [wave][column], Q = g + margin
    q4[wib][lane] = make_float4(gv[0] + MARGIN, gv[1] + MARGIN,
                                gv[2] + MARGIN, gv[3] + MARGIN);

    float a0 = 0.0f, a1 = 0.0f, a2 = 0.0f, a3 = 0.0f;

    __syncthreads();

    // max(x-b,0) = max(x,b)-b:  acc[r] += max(Q_r[c], g_r[lane]) * (lane<c);
    // one broadcast ds_read_b128 per column serves 4 rows.
    #pragma unroll
    for (int c = 1; c < NBEST; ++c) {
        float4 qa = q4[wib][c];
        float mm = (lane < c) ? 1.0f : 0.0f;           // shared by 4 rows
        a0 = fmaf(fmaxf(qa.x, gv[0]), mm, a0);
        a1 = fmaf(fmaxf(qa.y, gv[1]), mm, a1);
        a2 = fmaf(fmaxf(qa.z, gv[2]), mm, a2);
        a3 = fmaf(fmaxf(qa.w, gv[3]), mm, a3);
    }

    // Subtract g_i * count, tail-guard, mean denominator.
    const float cntf = (float)((NBEST - 1) - lane);
    float accs = 0.0f;
    accs += (b0 + 0 < B) ? fmaf(-gv[0], cntf, a0) : 0.0f;
    accs += (b0 + 1 < B) ? fmaf(-gv[1], cntf, a1) : 0.0f;
    accs += (b0 + 2 < B) ? fmaf(-gv[2], cntf, a2) : 0.0f;
    accs += (b0 + 3 < B) ? fmaf(-gv[3], cntf, a3) : 0.0f;
    int cnt = (NBEST - 1) - lane;                      // lane 63: acc==0
    float accv = accs / (float)(cnt > 0 ? cnt : 1);

    #pragma unroll
    for (int off = 32; off > 0; off >>= 1)
        accv += __shfl_down(accv, off);

    __shared__ float wsum[4];
    if (lane == 0) wsum[wib] = accv;
    __syncthreads();
    if (threadIdx.x != 0) return;
    float part = wsum[0] + wsum[1] + wsum[2] + wsum[3];

    if (gper == 0) { ws[16384 + blockIdx.x] = part; return; }

    // ---- two-level atomic cascade (counters/slots memset to 0 per call) ----
    char* base = (char*)ws;
    const unsigned g = (unsigned)blockIdx.x & 63u;     // spread co-dispatched
    float*        slot = (float*)(base + (size_t)g * 64);
    unsigned int* c1   = (unsigned int*)(base + 4096 + (size_t)g * 64);
    float*        s2   = (float*)(base + 8192);
    unsigned int* c2   = (unsigned int*)(base + 8196);

    atomicAdd(slot, part);
    __threadfence();                                   // release slot add
    unsigned o1 = atomicAdd(c1, 1u);
    if (o1 + 1u != (unsigned)gper) return;             // not group-last

    __threadfence();                                   // acquire peers' adds
    float gsum = atomicExch(slot, 0.0f);               // coherent group total
    atomicAdd(s2, gsum);
    __threadfence();                                   // release s2 add
    unsigned o2 = atomicAdd(c2, 1u);
    if (o2 + 1u != 64u) return;                        // not grand-last

    __threadfence();                                   // acquire all s2 adds
    out[0] = atomicExch(s2, 0.0f);
}

// Fallback finisher (only if grid isn't a multiple of 64 blocks).
__global__ __launch_bounds__(256)
void sml_reduce(const float* __restrict__ ws, float* __restrict__ out, int n)
{
    const int lane = threadIdx.x & 63;
    const int wid  = threadIdx.x >> 6;
    float s = 0.0f;
    for (int i = threadIdx.x; i < n; i += 256) s += ws[i + 16384];
    #pragma unroll
    for (int off = 32; off > 0; off >>= 1)
        s += __shfl_down(s, off);
    __shared__ float wsum[4];
    if (lane == 0) wsum[wid] = s;
    __syncthreads();
    if (threadIdx.x == 0)
        out[0] = wsum[0] + wsum[1] + wsum[2] + wsum[3];
}

extern "C" void kernel_launch(void* const* d_in, const int* in_sizes, int n_in,
                              void* d_out, int out_size, void* d_ws, size_t ws_size,
                              hipStream_t stream)
{
    const float* scores    = (const float*)d_in[0];
    const unsigned int* wr = (const unsigned int*)d_in[1];
    const int B = in_sizes[0] / NBEST;

    const int rows_per_block = 4 * RPW;                           // 16
    const int blocks = (B + rows_per_block - 1) / rows_per_block; // 1024
    const bool cascade = (blocks % 64 == 0) && (ws_size >= 16384);

    if (cascade) {
        // Zero slots + counters (8.25 KB) every call; capture-safe.
        hipMemsetAsync(d_ws, 0, 8448, stream);
        sml_kernel<<<blocks, 256, 0, stream>>>(scores, wr, (float*)d_ws,
                                               (float*)d_out, B, blocks / 64);
    } else {
        sml_kernel<<<blocks, 256, 0, stream>>>(scores, wr, (float*)d_ws,
                                               (float*)d_out, B, 0);
        sml_reduce<<<1, 256, 0, stream>>>((const float*)d_ws, (float*)d_out,
                                          blocks);
    }
}